// Round 1
// baseline (244.739 us; speedup 1.0000x reference)
//
#include <hip/hip_runtime.h>

#define B_N 32
#define C_N 256
#define HW_N 4096
#define K_N 64
#define NT 64
#define CHUNKS 8           // chunks per batch -> 256 blocks
#define SUBT 8             // 8 subtiles of 64 positions = 512 positions/block
#define NTHREADS 512
#define NBLOCKS (B_N * CHUNKS)

typedef __attribute__((ext_vector_type(8))) short short8;
typedef __attribute__((ext_vector_type(4))) float f32x4;

__device__ __forceinline__ unsigned short f2bf(float f) {
    unsigned int u = __builtin_bit_cast(unsigned int, f);
    u = (u + 0x7FFFu + ((u >> 16) & 1u)) >> 16;   // RNE
    return (unsigned short)u;
}

// ---- swizzled LDS index helpers (ushort-element index space) ----
// x_s [C][NT] (n innermost), swizzle spreads mm2 B-frag reads (lanes vary c)
__device__ __forceinline__ int xs_idx(int c, int n) {
    return (c * NT + n) ^ ((c & 7) << 3);
}
// xT_s [NT][C] (c innermost); sw = (n&7)^((n>>3)&7) makes BOTH the staging
// transpose-writes (lanes vary ng=n>>3 and c) and mm1 A-frag reads (lanes vary n&15)
// conflict-free
__device__ __forceinline__ int xts_idx(int n, int c) {
    int sw = (n & 7) ^ ((n >> 3) & 7);
    return (n * C_N + c) ^ (sw << 3);
}
// thT_s [K][NT] (n innermost), swizzle spreads mm2 A-frag reads (lanes vary k)
__device__ __forceinline__ int tht_idx(int k, int n) {
    return (k * NT + n) ^ ((k & 7) << 3);
}

__launch_bounds__(NTHREADS, 2)
__global__ void se_main_kernel(const float* __restrict__ x,
                               const float* __restrict__ clusters,
                               const float* __restrict__ scale,
                               float* __restrict__ ws_enc,
                               float* __restrict__ ws_ts) {
    __shared__ unsigned short x_s[C_N * NT];      // 32 KB bf16, [C][NT]
    __shared__ unsigned short xT_s[NT * C_N];     // 32 KB bf16, [NT][C]
    __shared__ float xcT_s[K_N * (NT + 1)];       // 16.6 KB, [K][NT+1] pad kills bank conflicts
    __shared__ unsigned short thT_s[K_N * NT];    // 8 KB bf16, [K][NT]
    __shared__ float xsqp_s[8 * NT];              // per-wave x_sq partials
    __shared__ float msm_s[8 * NT];               // softmax partial max
    __shared__ float mss_s[8 * NT];               // softmax partial sum
    __shared__ float csq_s[K_N];
    __shared__ float scl_s[K_N];

    const int tid = threadIdx.x;
    const int w = tid >> 6;         // wave 0..7
    const int l = tid & 63;         // lane
    const int gid = blockIdx.x;
    const int b = gid >> 3;
    const int chunk = gid & 7;

    // ---- c_sq and scale (one wave, fp32 exact) ----
    if (tid < K_N) {
        const float4* cr = (const float4*)(clusters + tid * C_N);
        float s = 0.f;
        #pragma unroll 16
        for (int i = 0; i < C_N / 4; ++i) {
            float4 v = cr[i];
            s += v.x * v.x + v.y * v.y + v.z * v.z + v.w * v.w;
        }
        csq_s[tid] = s;
        scl_s[tid] = scale[tid];
    }

    const int r16 = l & 15, g16 = l >> 4;
    const int u = l >> 3;           // staging c sub-row within wave
    const int ng = l & 7;           // staging n-group (8 consecutive n)

    // ---- mm1 clusters B-fragments held in registers (reused all subtiles) ----
    // mm1: xc(NT x K) = xf(NT x C) * B, B[c][k] = clusters[k][c]
    // wave w owns n-tile nt1 = w&3 and k-tiles {ktp, ktp+1}
    const int nt1 = w & 3;
    const int ktp = (w >> 2) * 2;
    short8 cb[2][8];
    #pragma unroll
    for (int t = 0; t < 2; ++t) {
        int k = (ktp + t) * 16 + r16;
        #pragma unroll
        for (int st = 0; st < 8; ++st) {
            int c0 = st * 32 + g16 * 8;
            const float* p = clusters + k * C_N + c0;
            short8 v;
            #pragma unroll
            for (int j = 0; j < 8; ++j) v[j] = (short)f2bf(p[j]);
            cb[t][st] = v;
        }
    }

    // mm2: enc(K x C) += thetaT(K x NT) * xf(NT x C); wave w owns c-tiles {2w, 2w+1}, all k-tiles
    const int ct0 = w * 2;
    f32x4 acc[4][2];
    #pragma unroll
    for (int a = 0; a < 4; ++a)
        #pragma unroll
        for (int cc = 0; cc < 2; ++cc) acc[a][cc] = (f32x4)0.f;
    float ts_reg[8];
    #pragma unroll
    for (int j = 0; j < 8; ++j) ts_reg[j] = 0.f;

    for (int s = 0; s < SUBT; ++s) {
        const int pos0 = chunk * (SUBT * NT) + s * NT;
        __syncthreads();  // BAR0: x_s/xT_s free (prev mm2 done)

        // ---- staging: read 64 n x 256 c fp32, write bf16 to both LDS layouts ----
        float4 va[4], vb[4];
        #pragma unroll
        for (int p = 0; p < 4; ++p) {
            int c = w * 8 + u + p * 64;
            const float* gp = x + ((size_t)(b * C_N + c) * HW_N + pos0 + ng * 8);
            va[p] = *(const float4*)gp;
            vb[p] = *(const float4*)(gp + 4);
        }
        float xsq8[8];
        #pragma unroll
        for (int i = 0; i < 8; ++i) xsq8[i] = 0.f;
        #pragma unroll
        for (int p = 0; p < 4; ++p) {
            int c = w * 8 + u + p * 64;
            float v[8] = {va[p].x, va[p].y, va[p].z, va[p].w,
                          vb[p].x, vb[p].y, vb[p].z, vb[p].w};
            unsigned short ub[8];
            short8 pk;
            #pragma unroll
            for (int i = 0; i < 8; ++i) {
                xsq8[i] += v[i] * v[i];
                ub[i] = f2bf(v[i]);
                pk[i] = (short)ub[i];
            }
            *(short8*)&x_s[xs_idx(c, ng * 8)] = pk;       // linear chunk, conflict-free
            #pragma unroll
            for (int i = 0; i < 8; ++i) {
                int n = ng * 8 + i;
                xT_s[xts_idx(n, c)] = ub[i];              // swizzled transpose, ~2-way
            }
        }
        // x_sq: reduce over u (lane bits 3..5), fp32 exact
        #pragma unroll
        for (int i = 0; i < 8; ++i) {
            float t = xsq8[i];
            t += __shfl_xor(t, 8, 64);
            t += __shfl_xor(t, 16, 64);
            t += __shfl_xor(t, 32, 64);
            xsq8[i] = t;
        }
        if (l < 8) {
            #pragma unroll
            for (int i = 0; i < 8; ++i) xsqp_s[w * NT + l * 8 + i] = xsq8[i];
        }
        __syncthreads(); // BAR1: xT_s, xsq partials ready

        // ---- mm1: xc = xf * B ; D rows = n, cols = k ----
        {
            f32x4 a0 = (f32x4)0.f, a1 = (f32x4)0.f;
            #pragma unroll
            for (int st = 0; st < 8; ++st) {
                int n = nt1 * 16 + r16;
                int c0 = st * 32 + g16 * 8;
                short8 af = *(const short8*)&xT_s[xts_idx(n, c0)];
                a0 = __builtin_amdgcn_mfma_f32_16x16x32_bf16(af, cb[0][st], a0, 0, 0, 0);
                a1 = __builtin_amdgcn_mfma_f32_16x16x32_bf16(af, cb[1][st], a1, 0, 0, 0);
            }
            #pragma unroll
            for (int rr = 0; rr < 4; ++rr) {
                int n = nt1 * 16 + g16 * 4 + rr;
                xcT_s[(ktp * 16 + r16) * (NT + 1) + n] = a0[rr];
                xcT_s[((ktp + 1) * 16 + r16) * (NT + 1) + n] = a1[rr];
            }
        }
        __syncthreads(); // BAR2: xcT ready

        // ---- softmax over K=64, thread owns position n=l, wave owns 8 k's ----
        float xsq = 0.f;
        #pragma unroll
        for (int ww = 0; ww < 8; ++ww) xsq += xsqp_s[ww * NT + l];
        float lg[8];
        float m8 = -1e30f;
        #pragma unroll
        for (int j = 0; j < 8; ++j) {
            int k = w * 8 + j;
            float xc = xcT_s[k * (NT + 1) + l];
            lg[j] = scl_s[k] * (xsq - 2.f * xc + csq_s[k]);
            m8 = fmaxf(m8, lg[j]);
        }
        msm_s[w * NT + l] = m8;
        __syncthreads(); // BAR3

        float M = msm_s[l];
        #pragma unroll
        for (int ww = 1; ww < 8; ++ww) M = fmaxf(M, msm_s[ww * NT + l]);
        float e[8], s8 = 0.f;
        #pragma unroll
        for (int j = 0; j < 8; ++j) { e[j] = __expf(lg[j] - M); s8 += e[j]; }
        mss_s[w * NT + l] = s8;
        __syncthreads(); // BAR4

        float S = 0.f;
        #pragma unroll
        for (int ww = 0; ww < 8; ++ww) S += mss_s[ww * NT + l];
        float rin = __fdividef(1.0f, S);
        #pragma unroll
        for (int j = 0; j < 8; ++j) {
            float th = e[j] * rin;
            thT_s[tht_idx(w * 8 + j, l)] = f2bf(th);
            float t = th;                      // theta_sum: fp32 butterfly over n
            t += __shfl_xor(t, 1, 64);
            t += __shfl_xor(t, 2, 64);
            t += __shfl_xor(t, 4, 64);
            t += __shfl_xor(t, 8, 64);
            t += __shfl_xor(t, 16, 64);
            t += __shfl_xor(t, 32, 64);
            ts_reg[j] += t;
        }
        __syncthreads(); // BAR5: thT ready

        // ---- mm2: acc[kt][cc] += thetaT-tile * xf-tile ----
        #pragma unroll
        for (int st = 0; st < 2; ++st) {
            int n0 = st * 32 + g16 * 8;
            short8 av[4];
            #pragma unroll
            for (int kt = 0; kt < 4; ++kt)
                av[kt] = *(const short8*)&thT_s[tht_idx(kt * 16 + r16, n0)];
            #pragma unroll
            for (int cc = 0; cc < 2; ++cc) {
                int c = (ct0 + cc) * 16 + r16;
                short8 bv = *(const short8*)&x_s[xs_idx(c, n0)];
                #pragma unroll
                for (int kt = 0; kt < 4; ++kt)
                    acc[kt][cc] = __builtin_amdgcn_mfma_f32_16x16x32_bf16(av[kt], bv, acc[kt][cc], 0, 0, 0);
            }
        }
    }

    // ---- write per-block partials (D rows = k, cols = c) ----
    float* eb = ws_enc + (size_t)gid * (K_N * C_N);
    #pragma unroll
    for (int kt = 0; kt < 4; ++kt) {
        #pragma unroll
        for (int cc = 0; cc < 2; ++cc) {
            int c = (ct0 + cc) * 16 + r16;
            #pragma unroll
            for (int rr = 0; rr < 4; ++rr) {
                int k = kt * 16 + g16 * 4 + rr;
                eb[k * C_N + c] = acc[kt][cc][rr];
            }
        }
    }
    if (l == 0) {
        #pragma unroll
        for (int j = 0; j < 8; ++j) ws_ts[gid * K_N + w * 8 + j] = ts_reg[j];
    }
}

__global__ void se_reduce_kernel(const float* __restrict__ ws_enc,
                                 const float* __restrict__ ws_ts,
                                 const float* __restrict__ clusters,
                                 float* __restrict__ out) {
    int tid = blockIdx.x * 256 + threadIdx.x;   // 131072 threads: (b,k,c4)
    int c4 = tid & 63;
    int k = (tid >> 6) & 63;
    int b = tid >> 12;
    float4 a = {0.f, 0.f, 0.f, 0.f};
    size_t base = (size_t)(b * CHUNKS) * (K_N * C_N) + k * C_N + c4 * 4;
    #pragma unroll
    for (int p = 0; p < CHUNKS; ++p) {
        float4 v = *(const float4*)(ws_enc + base + (size_t)p * (K_N * C_N));
        a.x += v.x; a.y += v.y; a.z += v.z; a.w += v.w;
    }
    float ts = 0.f;
    #pragma unroll
    for (int p = 0; p < CHUNKS; ++p) ts += ws_ts[(b * CHUNKS + p) * K_N + k];
    float4 cl = *(const float4*)(clusters + k * C_N + c4 * 4);
    float4 o;
    o.x = a.x - ts * cl.x;
    o.y = a.y - ts * cl.y;
    o.z = a.z - ts * cl.z;
    o.w = a.w - ts * cl.w;
    *(float4*)(out + (size_t)(b * K_N + k) * C_N + c4 * 4) = o;
}

extern "C" void kernel_launch(void* const* d_in, const int* in_sizes, int n_in,
                              void* d_out, int out_size, void* d_ws, size_t ws_size,
                              hipStream_t stream) {
    const float* x        = (const float*)d_in[0];
    const float* clusters = (const float*)d_in[1];
    const float* scale    = (const float*)d_in[2];
    float* out    = (float*)d_out;
    float* ws_enc = (float*)d_ws;                                  // 256*64*256 f32 = 16 MB
    float* ws_ts  = ws_enc + (size_t)NBLOCKS * K_N * C_N;          // + 256*64 f32

    se_main_kernel<<<NBLOCKS, NTHREADS, 0, stream>>>(x, clusters, scale, ws_enc, ws_ts);
    se_reduce_kernel<<<(B_N * K_N * 64) / 256, 256, 0, stream>>>(ws_enc, ws_ts, clusters, out);
}